// Round 9
// baseline (176.055 us; speedup 1.0000x reference)
//
#include <hip/hip_runtime.h>
#include <hip/hip_bf16.h>
#include <math.h>

#define N_NODES 50000
#define N_EDGES 800000
#define F_IN    64
#define F_HID   128
#define F_OUT   40
#define H2_STR  64        // padded h2b row stride (bf16)
#define SCAN_BLOCKS 196   // ceil(50000/256)
#define SEG_NODES 6250    // 50000 / 8 segments (one per XCD)
#define SCAT_CHUNKS 256   // edge chunks; grid = 8 * SCAT_CHUNKS
#define SCAT_CE 3125      // edges per chunk = 800000 / 256

typedef unsigned short ushort8_t __attribute__((ext_vector_type(8)));

__device__ __forceinline__ float bf2f(unsigned short u) {
    union { float f; unsigned int i; } x; x.i = ((unsigned int)u) << 16; return x.f;
}
__device__ __forceinline__ unsigned short f2bf(float f) {
    union { __hip_bfloat16 h; unsigned short u; } x; x.h = __float2bfloat16(f); return x.u;
}

// ---------------- fused: x->bf16 + zero counters ----------------

__global__ void k_x2bf_zero(const float* __restrict__ x, __hip_bfloat16* __restrict__ xb,
                            int* __restrict__ cnt) {
    int i = blockIdx.x * 256 + threadIdx.x;   // over N*16 float4s
    if (i < N_NODES) cnt[i] = 0;
    if (i >= N_NODES * 16) return;
    float4 v = ((const float4*)x)[i];
    __hip_bfloat16 o[4] = { __float2bfloat16(v.x), __float2bfloat16(v.y),
                            __float2bfloat16(v.z), __float2bfloat16(v.w) };
    ((ushort4*)xb)[i] = *(const ushort4*)o;
}

__global__ void k_count(const int* __restrict__ ei, int* __restrict__ cnt) {
    int e = blockIdx.x * blockDim.x + threadIdx.x;
    if (e < N_EDGES) atomicAdd(&cnt[ei[N_EDGES + e]], 1);   // target node
}

// phase A: per-block reduction of 256 counts -> blockSums[b]
__global__ __launch_bounds__(256) void k_scanA(const int* __restrict__ cnt,
                                               int* __restrict__ blockSums) {
    __shared__ int sw[4];
    int i = blockIdx.x * 256 + threadIdx.x;
    int v = (i < N_NODES) ? cnt[i] : 0;
    #pragma unroll
    for (int o = 32; o > 0; o >>= 1) v += __shfl_xor(v, o);
    int lane = threadIdx.x & 63, w = threadIdx.x >> 6;
    if (lane == 0) sw[w] = v;
    __syncthreads();
    if (threadIdx.x == 0) blockSums[blockIdx.x] = sw[0] + sw[1] + sw[2] + sw[3];
}

// phase C (fused with B): every block redundantly scans the 196 block sums,
// then does its intra-block exclusive scan; emits start/cursor/dinv
__global__ __launch_bounds__(256) void k_scanC(int* __restrict__ startArr,
                                               const int* __restrict__ blockSums,
                                               int* __restrict__ cursor,
                                               float* __restrict__ dinv) {
    __shared__ int sbs[256];
    __shared__ int part[256];
    int t = threadIdx.x;
    int bv = (t < SCAN_BLOCKS) ? blockSums[t] : 0;
    sbs[t] = bv;
    __syncthreads();
    for (int off = 1; off < 256; off <<= 1) {
        int u = (t >= off) ? sbs[t - off] : 0;
        __syncthreads();
        sbs[t] += u;
        __syncthreads();
    }
    int blockOff = (blockIdx.x == 0) ? 0 : sbs[blockIdx.x - 1];

    int i = blockIdx.x * 256 + t;
    int v = (i < N_NODES) ? startArr[i] : 0;
    part[t] = v;
    __syncthreads();
    for (int off = 1; off < 256; off <<= 1) {
        int u = (t >= off) ? part[t - off] : 0;
        __syncthreads();
        part[t] += u;
        __syncthreads();
    }
    if (i < N_NODES) {
        int pos = blockOff + part[t] - v;   // exclusive prefix
        startArr[i] = pos;
        cursor[i]   = pos;
        dinv[i]     = rsqrtf((float)v + 1.0f);           // +1 self loop
    }
    if (i == 0) startArr[N_NODES] = N_EDGES;
}

// segmented scatter (XCD write locality); also precomputes the per-edge
// normalization weight so the gathers never touch dinv randomly.
// csrw[pos] = { source row, dinv[r]*dinv[c] }
__global__ __launch_bounds__(256) void k_scatter(const int* __restrict__ ei,
                                                 int* __restrict__ cursor,
                                                 int2* __restrict__ csrw,
                                                 const float* __restrict__ dinv) {
    int seg = blockIdx.x & 7;
    int lo = seg * SEG_NODES, hi = lo + SEG_NODES;
    int e0 = (blockIdx.x >> 3) * SCAT_CE;
    int e1 = e0 + SCAT_CE; if (e1 > N_EDGES) e1 = N_EDGES;
    for (int e = e0 + threadIdx.x; e < e1; e += 256) {
        int c = ei[N_EDGES + e];
        if (c >= lo && c < hi) {
            int r = ei[e];
            float w = dinv[r] * dinv[c];
            int pos = atomicAdd(&cursor[c], 1);
            csrw[pos] = make_int2(r, __float_as_int(w));
        }
    }
}

// ---------------- layer 1 gather: wave = node; 8 rows/instr, 16B/lane ----------------
// lane = (o,s): o = row-in-group (0..7), s = 8-feature chunk (0..7); bf16 out

__global__ __launch_bounds__(256) void k_agg1(const __hip_bfloat16* __restrict__ xb,
                                              const float* __restrict__ dinv,
                                              const int* __restrict__ startArr,
                                              const int2* __restrict__ csrw,
                                              __hip_bfloat16* __restrict__ agg1b) {
    int wid  = (blockIdx.x * 256 + threadIdx.x) >> 6;
    int lane = threadIdx.x & 63;
    if (wid >= N_NODES) return;
    const int o = lane >> 3, s = lane & 7;
    const int c = wid;
    const float dc = dinv[c];
    float acc[8] = {};

    if (o == 0) {   // self loop
        float w = dc * dc;
        ushort8_t v = *(const ushort8_t*)(xb + (size_t)c * F_IN + s * 8);
        #pragma unroll
        for (int k = 0; k < 8; ++k) acc[k] = fmaf(bf2f(v[k]), w, acc[k]);
    }

    int e = startArr[c], eend = startArr[c + 1];
    while (e < eend) {
        int take = eend - e; if (take > 64) take = 64;
        int r = 0; float w = 0.f;   // lanes >= take keep w=0 -> masked
        if (lane < take) { int2 p = csrw[e + lane]; r = p.x; w = __int_as_float(p.y); }
        for (int j = 0; j < take; j += 16) {
            int ia = j + o;      ia = ia > 63 ? 63 : ia;
            int ib = j + 8 + o;  ib = ib > 63 ? 63 : ib;
            int   ra = __shfl(r, ia), rb = __shfl(r, ib);
            float wa = __shfl(w, ia), wb = __shfl(w, ib);
            ushort8_t va = *(const ushort8_t*)(xb + (size_t)ra * F_IN + s * 8);
            ushort8_t vb = *(const ushort8_t*)(xb + (size_t)rb * F_IN + s * 8);
            #pragma unroll
            for (int k = 0; k < 8; ++k) acc[k] = fmaf(bf2f(va[k]), wa, acc[k]);
            #pragma unroll
            for (int k = 0; k < 8; ++k) acc[k] = fmaf(bf2f(vb[k]), wb, acc[k]);
        }
        e += take;
    }

    #pragma unroll
    for (int k = 0; k < 8; ++k) {
        acc[k] += __shfl_xor(acc[k], 8);
        acc[k] += __shfl_xor(acc[k], 16);
        acc[k] += __shfl_xor(acc[k], 32);
    }
    if (o == 0) {
        ushort8_t o8;
        #pragma unroll
        for (int k = 0; k < 8; ++k) o8[k] = f2bf(acc[k]);
        *(ushort8_t*)(agg1b + (size_t)c * F_IN + s * 8) = o8;
    }
}

// ---------------- fused GEMM: h2b = (PReLU(agg1b@W1+b1)) @ W2, all in one tile ----
// stage 1: 64x64 @ 64x128 -> sH (bf16); stage 2: 64x128 @ 128x40 -> h2b (padded)

__global__ __launch_bounds__(256) void k_gemm12(const __hip_bfloat16* __restrict__ agg1b,
                                                const float* __restrict__ W1,
                                                const float* __restrict__ b1,
                                                const float* __restrict__ alpha,
                                                const float* __restrict__ W2,
                                                __hip_bfloat16* __restrict__ h2b) {
    __shared__ float sW1[F_IN][F_HID];              // 32 KB
    __shared__ float sW2[F_HID][F_OUT];             // 20 KB
    __shared__ float sb[F_HID];
    __shared__ __hip_bfloat16 sA[64][F_IN + 8];     // 9 KB
    __shared__ __hip_bfloat16 sH[64][F_HID + 8];    // 17 KB
    int t = threadIdx.x;
    int row0 = blockIdx.x * 64;

    for (int i = t; i < (F_IN * F_HID) / 4; i += 256)
        ((float4*)sW1)[i] = ((const float4*)W1)[i];
    for (int i = t; i < (F_HID * F_OUT) / 4; i += 256)
        ((float4*)sW2)[i] = ((const float4*)W2)[i];
    if (t < F_HID) sb[t] = b1[t];
    for (int i = t; i < 64 * (F_IN / 8); i += 256) {    // 16B chunks: 512 total
        int r = i >> 3, c = (i & 7) * 8;
        int rs = row0 + r; if (rs >= N_NODES) rs = N_NODES - 1;
        *(float4*)&sA[r][c] = *(const float4*)(agg1b + (size_t)rs * F_IN + c);
    }
    __syncthreads();

    // stage 1: thread = 4 rows x 8 cols
    {
        const int ri = (t >> 4) * 4;
        const int cj = (t & 15) * 8;
        float acc[4][8] = {};
        #pragma unroll 4
        for (int k = 0; k < F_IN; ++k) {
            float a0 = bf2f(*(const unsigned short*)&sA[ri + 0][k]);
            float a1 = bf2f(*(const unsigned short*)&sA[ri + 1][k]);
            float a2 = bf2f(*(const unsigned short*)&sA[ri + 2][k]);
            float a3 = bf2f(*(const unsigned short*)&sA[ri + 3][k]);
            float4 bA = *(const float4*)&sW1[k][cj];
            float4 bB = *(const float4*)&sW1[k][cj + 4];
            float bv[8] = { bA.x, bA.y, bA.z, bA.w, bB.x, bB.y, bB.z, bB.w };
            #pragma unroll
            for (int cc = 0; cc < 8; ++cc) {
                acc[0][cc] = fmaf(a0, bv[cc], acc[0][cc]);
                acc[1][cc] = fmaf(a1, bv[cc], acc[1][cc]);
                acc[2][cc] = fmaf(a2, bv[cc], acc[2][cc]);
                acc[3][cc] = fmaf(a3, bv[cc], acc[3][cc]);
            }
        }
        const float al = alpha[0];
        #pragma unroll
        for (int rr = 0; rr < 4; ++rr) {
            #pragma unroll
            for (int cc = 0; cc < 8; ++cc) {
                float v = acc[rr][cc] + sb[cj + cc];
                v = (v >= 0.f) ? v : al * v;
                *(unsigned short*)&sH[ri + rr][cj + cc] = f2bf(v);
            }
        }
    }
    __syncthreads();

    // stage 2: thread = 2 rows x 5 cols
    {
        const int ri = (t >> 3) * 2;
        const int cj = (t & 7) * 5;
        float acc[2][5] = {};
        #pragma unroll 8
        for (int k = 0; k < F_HID; ++k) {
            float a0 = bf2f(*(const unsigned short*)&sH[ri + 0][k]);
            float a1 = bf2f(*(const unsigned short*)&sH[ri + 1][k]);
            #pragma unroll
            for (int cc = 0; cc < 5; ++cc) {
                float b = sW2[k][cj + cc];
                acc[0][cc] = fmaf(a0, b, acc[0][cc]);
                acc[1][cc] = fmaf(a1, b, acc[1][cc]);
            }
        }
        #pragma unroll
        for (int rr = 0; rr < 2; ++rr) {
            int r = row0 + ri + rr;
            if (r >= N_NODES) continue;
            #pragma unroll
            for (int cc = 0; cc < 5; ++cc)
                h2b[(size_t)r * H2_STR + cj + cc] = __float2bfloat16(acc[rr][cc]);
        }
    }
    // padding cols 40..63 are never read (agg2 loads only s<5 chunks) -> no zeroing
}

// ---------------- layer 2 gather + bias + log_softmax ----------------
// (o,s) scheme; only s<5 chunks are loaded (40 valid feats); h2b stride 64

__global__ __launch_bounds__(256) void k_agg2_lsm(const __hip_bfloat16* __restrict__ h2b,
                                                  const float* __restrict__ dinv,
                                                  const int* __restrict__ startArr,
                                                  const int2* __restrict__ csrw,
                                                  const float* __restrict__ b2,
                                                  float* __restrict__ out) {
    int wid  = (blockIdx.x * 256 + threadIdx.x) >> 6;
    int lane = threadIdx.x & 63;
    if (wid >= N_NODES) return;
    const int o = lane >> 3, s = lane & 7;
    const int c = wid;
    const float dc = dinv[c];
    float acc[8] = {};

    if (o == 0 && s < 5) {   // self loop
        float w = dc * dc;
        ushort8_t v = *(const ushort8_t*)(h2b + (size_t)c * H2_STR + s * 8);
        #pragma unroll
        for (int k = 0; k < 8; ++k) acc[k] = fmaf(bf2f(v[k]), w, acc[k]);
    }

    int e = startArr[c], eend = startArr[c + 1];
    while (e < eend) {
        int take = eend - e; if (take > 64) take = 64;
        int r = 0; float w = 0.f;
        if (lane < take) { int2 p = csrw[e + lane]; r = p.x; w = __int_as_float(p.y); }
        for (int j = 0; j < take; j += 16) {
            int ia = j + o;      ia = ia > 63 ? 63 : ia;
            int ib = j + 8 + o;  ib = ib > 63 ? 63 : ib;
            int   ra = __shfl(r, ia), rb = __shfl(r, ib);
            float wa = __shfl(w, ia), wb = __shfl(w, ib);
            ushort8_t va = {}, vb = {};
            if (s < 5) {
                va = *(const ushort8_t*)(h2b + (size_t)ra * H2_STR + s * 8);
                vb = *(const ushort8_t*)(h2b + (size_t)rb * H2_STR + s * 8);
            }
            #pragma unroll
            for (int k = 0; k < 8; ++k) acc[k] = fmaf(bf2f(va[k]), wa, acc[k]);
            #pragma unroll
            for (int k = 0; k < 8; ++k) acc[k] = fmaf(bf2f(vb[k]), wb, acc[k]);
        }
        e += take;
    }

    #pragma unroll
    for (int k = 0; k < 8; ++k) {
        acc[k] += __shfl_xor(acc[k], 8);
        acc[k] += __shfl_xor(acc[k], 16);
        acc[k] += __shfl_xor(acc[k], 32);
    }

    // bias + log_softmax in (o,s) layout; feats f = s*8+k valid iff f < 40 (s < 5)
    float vloc[8];
    float m = -INFINITY;
    if (s < 5) {
        float4 p = *(const float4*)(b2 + s * 8);
        float4 q = *(const float4*)(b2 + s * 8 + 4);
        float bb[8] = { p.x, p.y, p.z, p.w, q.x, q.y, q.z, q.w };
        #pragma unroll
        for (int k = 0; k < 8; ++k) { vloc[k] = acc[k] + bb[k]; m = fmaxf(m, vloc[k]); }
    } else {
        #pragma unroll
        for (int k = 0; k < 8; ++k) vloc[k] = -INFINITY;
    }
    m = fmaxf(m, __shfl_xor(m, 1));
    m = fmaxf(m, __shfl_xor(m, 2));
    m = fmaxf(m, __shfl_xor(m, 4));
    float sum = 0.f;
    if (s < 5) {
        #pragma unroll
        for (int k = 0; k < 8; ++k) sum += expf(vloc[k] - m);
    }
    sum += __shfl_xor(sum, 1);
    sum += __shfl_xor(sum, 2);
    sum += __shfl_xor(sum, 4);
    float ls = m + logf(sum);

    if (o == 0 && s < 5) {
        float4 a = { vloc[0] - ls, vloc[1] - ls, vloc[2] - ls, vloc[3] - ls };
        float4 b = { vloc[4] - ls, vloc[5] - ls, vloc[6] - ls, vloc[7] - ls };
        *(float4*)(out + (size_t)c * F_OUT + s * 8)     = a;
        *(float4*)(out + (size_t)c * F_OUT + s * 8 + 4) = b;
    }
}

// ---------------- launch ----------------

extern "C" void kernel_launch(void* const* d_in, const int* in_sizes, int n_in,
                              void* d_out, int out_size, void* d_ws, size_t ws_size,
                              hipStream_t stream) {
    const float* x     = (const float*)d_in[0];
    const int*   ei    = (const int*)d_in[1];
    const float* W1    = (const float*)d_in[2];
    const float* b1    = (const float*)d_in[3];
    const float* W2    = (const float*)d_in[4];
    const float* b2    = (const float*)d_in[5];
    const float* alpha = (const float*)d_in[6];
    float* out = (float*)d_out;

    // workspace layout (elements)
    int*   startArr  = (int*)d_ws;                        // 50048 ints
    int*   cursor    = startArr + 50048;                  // 50048
    int*   blockSums = cursor + 50048;                    // 256
    int2*  csrw      = (int2*)(blockSums + 256);          // 800000 int2 (8B-aligned)
    float* dinv      = (float*)(csrw + N_EDGES);          // 50048 floats
    __hip_bfloat16* xb    = (__hip_bfloat16*)(dinv + 50048);   // N*64 bf16 (6.4 MB)
    __hip_bfloat16* agg1b = xb + (size_t)N_NODES * F_IN;       // N*64 bf16
    __hip_bfloat16* h2b   = agg1b + (size_t)N_NODES * F_IN;    // N*64 bf16 padded

    const int B = 256;

    hipLaunchKernelGGL(k_x2bf_zero, dim3((N_NODES * 16 + B - 1) / B), dim3(B), 0, stream, x, xb, startArr);
    hipLaunchKernelGGL(k_count,     dim3((N_EDGES + B - 1) / B), dim3(B), 0, stream, ei, startArr);
    hipLaunchKernelGGL(k_scanA,     dim3(SCAN_BLOCKS), dim3(B), 0, stream, startArr, blockSums);
    hipLaunchKernelGGL(k_scanC,     dim3(SCAN_BLOCKS), dim3(B), 0, stream, startArr, blockSums, cursor, dinv);
    hipLaunchKernelGGL(k_scatter,   dim3(8 * SCAT_CHUNKS), dim3(B), 0, stream, ei, cursor, csrw, dinv);

    hipLaunchKernelGGL(k_agg1,   dim3((N_NODES * 64 + B - 1) / B), dim3(B), 0, stream, xb, dinv, startArr, csrw, agg1b);
    hipLaunchKernelGGL(k_gemm12, dim3((N_NODES + 63) / 64), dim3(B), 0, stream, agg1b, W1, b1, alpha, W2, h2b);
    hipLaunchKernelGGL(k_agg2_lsm, dim3((N_NODES * 64 + B - 1) / B), dim3(B), 0, stream,
                       h2b, dinv, startArr, csrw, b2, out);
}